// Round 1
// 378.979 us; speedup vs baseline: 1.0180x; 1.0180x over previous
//
#include <hip/hip_runtime.h>

#define B_SZ 2
#define E_SZ 1024
#define C_SZ 128
#define R_REL 32
#define TS 64
#define TO 64

typedef float f32x4 __attribute__((ext_vector_type(4)));

// ---------------------------------------------------------------------------
// K1: Gram tiles. G[b,s,o] = sum_c x[b,s,c] * x[b,o,c]
// Identical staging + accumulation order to the verified fused kernel
// (same numerics), but writes the 64x64 G tile to workspace instead of
// streaming R. 512 blocks, runs once, ~10 us.
// ---------------------------------------------------------------------------
__global__ __launch_bounds__(256, 2) void gram_tile(
        const float* __restrict__ x,
        float* __restrict__ G) {
    __shared__ float xs[TS][C_SZ + 4];
    __shared__ float xo[TO][C_SZ + 4];

    const int b  = blockIdx.z;
    const int s0 = blockIdx.y * TS;
    const int o0 = blockIdx.x * TO;
    const int tid = threadIdx.x;

    const float4* src_s = (const float4*)(x + (size_t)b * E_SZ * C_SZ + (size_t)s0 * C_SZ);
    const float4* src_o = (const float4*)(x + (size_t)b * E_SZ * C_SZ + (size_t)o0 * C_SZ);
    #pragma unroll
    for (int i = tid; i < TS * (C_SZ / 4); i += 256) {
        const int row = i >> 5;
        const int col = (i & 31) << 2;
        *(float4*)&xs[row][col] = src_s[i];
        *(float4*)&xo[row][col] = src_o[i];
    }
    __syncthreads();

    const int tx = tid & 15;
    const int ty = tid >> 4;
    const int si = ty << 2;
    const int oj = tx << 2;

    float acc[4][4];
    #pragma unroll
    for (int ii = 0; ii < 4; ++ii)
        #pragma unroll
        for (int jj = 0; jj < 4; ++jj) acc[ii][jj] = 0.f;

    #pragma unroll 4
    for (int c = 0; c < C_SZ; c += 4) {
        float4 a[4], bb[4];
        #pragma unroll
        for (int ii = 0; ii < 4; ++ii) a[ii]  = *(const float4*)&xs[si + ii][c];
        #pragma unroll
        for (int jj = 0; jj < 4; ++jj) bb[jj] = *(const float4*)&xo[oj + jj][c];
        #pragma unroll
        for (int ii = 0; ii < 4; ++ii) {
            #pragma unroll
            for (int jj = 0; jj < 4; ++jj) {
                acc[ii][jj] += a[ii].x * bb[jj].x + a[ii].y * bb[jj].y
                             + a[ii].z * bb[jj].z + a[ii].w * bb[jj].w;
            }
        }
    }

    // Coalesced float4 writes of the G tile (kept in cache for K2 — not NT).
    #pragma unroll
    for (int ii = 0; ii < 4; ++ii) {
        float4 gv;
        gv.x = acc[ii][0]; gv.y = acc[ii][1]; gv.z = acc[ii][2]; gv.w = acc[ii][3];
        *(float4*)(G + ((size_t)b * E_SZ + (size_t)(s0 + si + ii)) * E_SZ + o0 + oj) = gv;
    }
}

// ---------------------------------------------------------------------------
// K2: pure stream. out[b,s,r,o] = G[b,s,o] * R[r,s,o]
// Block = (s, r-chunk of 16); thread t owns float4 lane o4 = t for BOTH
// batches -> every R element is fetched exactly once from HBM.
// No LDS, tiny VGPR footprint -> full occupancy; 2048 blocks.
// All accesses: 4 KB contiguous per wave. NT loads/stores keep L2 clean.
// ---------------------------------------------------------------------------
__global__ __launch_bounds__(256, 8) void scale_stream(
        const float* __restrict__ G,
        const float* __restrict__ R,
        float* __restrict__ out) {
    const int o4 = threadIdx.x;            // 0..255 float4 columns
    const int s  = blockIdx.x;             // 0..1023
    const int r0 = blockIdx.y * (R_REL / 2);  // 0 or 16

    const f32x4* G4 = (const f32x4*)G;
    const f32x4* R4 = (const f32x4*)R;
    f32x4*       O4 = (f32x4*)out;

    const f32x4 g0 = G4[(size_t)s * (E_SZ / 4) + o4];
    const f32x4 g1 = G4[((size_t)E_SZ + s) * (E_SZ / 4) + o4];

    const f32x4* rp  = R4 + ((size_t)r0 * E_SZ + s) * (E_SZ / 4) + o4;
    f32x4*       op0 = O4 + (((size_t)s) * R_REL + r0) * (E_SZ / 4) + o4;
    f32x4*       op1 = O4 + (((size_t)(E_SZ + s)) * R_REL + r0) * (E_SZ / 4) + o4;

    #pragma unroll 4
    for (int r = 0; r < R_REL / 2; ++r) {
        f32x4 rv = __builtin_nontemporal_load(rp);
        __builtin_nontemporal_store(rv * g0, op0);
        __builtin_nontemporal_store(rv * g1, op1);
        rp  += (size_t)E_SZ * E_SZ / 4;   // next r slab of R
        op0 += E_SZ / 4;                  // next r row of out
        op1 += E_SZ / 4;
    }
}

// ---------------------------------------------------------------------------
// Fallback (workspace too small): the previous verified fused kernel.
// ---------------------------------------------------------------------------
__global__ __launch_bounds__(256, 2) void rescal_fused(
        const float* __restrict__ x,
        const float* __restrict__ R,
        float* __restrict__ out) {
    __shared__ float xs[TS][C_SZ + 4];
    __shared__ float xo[TO][C_SZ + 4];

    const int b  = blockIdx.z;
    const int s0 = blockIdx.y * TS;
    const int o0 = blockIdx.x * TO;
    const int tid = threadIdx.x;

    const float4* src_s = (const float4*)(x + (size_t)b * E_SZ * C_SZ + (size_t)s0 * C_SZ);
    const float4* src_o = (const float4*)(x + (size_t)b * E_SZ * C_SZ + (size_t)o0 * C_SZ);
    #pragma unroll
    for (int i = tid; i < TS * (C_SZ / 4); i += 256) {
        const int row = i >> 5;
        const int col = (i & 31) << 2;
        *(float4*)&xs[row][col] = src_s[i];
        *(float4*)&xo[row][col] = src_o[i];
    }
    __syncthreads();

    const int tx = tid & 15;
    const int ty = tid >> 4;
    const int si = ty << 2;
    const int oj = tx << 2;

    float acc[4][4];
    #pragma unroll
    for (int ii = 0; ii < 4; ++ii)
        #pragma unroll
        for (int jj = 0; jj < 4; ++jj) acc[ii][jj] = 0.f;

    #pragma unroll 4
    for (int c = 0; c < C_SZ; c += 4) {
        float4 a[4], bb[4];
        #pragma unroll
        for (int ii = 0; ii < 4; ++ii) a[ii]  = *(const float4*)&xs[si + ii][c];
        #pragma unroll
        for (int jj = 0; jj < 4; ++jj) bb[jj] = *(const float4*)&xo[oj + jj][c];
        #pragma unroll
        for (int ii = 0; ii < 4; ++ii) {
            #pragma unroll
            for (int jj = 0; jj < 4; ++jj) {
                acc[ii][jj] += a[ii].x * bb[jj].x + a[ii].y * bb[jj].y
                             + a[ii].z * bb[jj].z + a[ii].w * bb[jj].w;
            }
        }
    }

    const size_t out_base = ((size_t)b * E_SZ + (size_t)s0) * (size_t)(R_REL * E_SZ) + o0;
    #pragma unroll 1
    for (int r = 0; r < R_REL; ++r) {
        const float* Rp = R + (size_t)r * (E_SZ * E_SZ) + (size_t)s0 * E_SZ + o0;
        float* op = out + out_base + (size_t)r * E_SZ;
        #pragma unroll
        for (int ii = 0; ii < 4; ++ii) {
            const float4 rv = *(const float4*)(Rp + (size_t)(si + ii) * E_SZ + oj);
            float4 ov;
            ov.x = acc[ii][0] * rv.x;
            ov.y = acc[ii][1] * rv.y;
            ov.z = acc[ii][2] * rv.z;
            ov.w = acc[ii][3] * rv.w;
            *(float4*)(op + (size_t)(si + ii) * (R_REL * E_SZ) + oj) = ov;
        }
    }
}

extern "C" void kernel_launch(void* const* d_in, const int* in_sizes, int n_in,
                              void* d_out, int out_size, void* d_ws, size_t ws_size,
                              hipStream_t stream) {
    const float* x = (const float*)d_in[0];
    const float* R = (const float*)d_in[1];
    float* out = (float*)d_out;

    const size_t g_bytes = (size_t)B_SZ * E_SZ * E_SZ * sizeof(float);  // 8 MiB
    if (ws_size >= g_bytes && d_ws != nullptr) {
        float* G = (float*)d_ws;
        dim3 g1(E_SZ / TO, E_SZ / TS, B_SZ);          // 512 blocks
        gram_tile<<<g1, 256, 0, stream>>>(x, G);
        dim3 g2(E_SZ, R_REL / 16);                    // 2048 blocks
        scale_stream<<<g2, 256, 0, stream>>>(G, R, out);
    } else {
        dim3 grid(E_SZ / TO, E_SZ / TS, B_SZ);
        rescal_fused<<<grid, 256, 0, stream>>>(x, R, out);
    }
}